// Round 1
// baseline (70.318 us; speedup 1.0000x reference)
//
#include <hip/hip_runtime.h>
#include <math.h>

#define HD 256
#define SD 768
#define D2 512
#define NE 8
#define NB 32

__device__ __forceinline__ float gelu_exact(float x) {
    return 0.5f * x * (1.0f + erff(x * 0.70710678118654752f));
}

// Kernel A: per-batch-row pipeline: smiles->proj->v->attended->fused->gate->softmax->top2
__global__ __launch_bounds__(256) void stageA(
    const float* __restrict__ smiles,
    const float* __restrict__ sW, const float* __restrict__ sb,
    const float* __restrict__ Wv, const float* __restrict__ bv,
    const float* __restrict__ Wo, const float* __restrict__ bo,
    const float* __restrict__ gW, const float* __restrict__ gb,
    float* __restrict__ fused_out, float* __restrict__ probs_out,
    float* __restrict__ p_out, int* __restrict__ sel_out)
{
    int b = blockIdx.x, t = threadIdx.x;
    __shared__ float s_in[SD];
    __shared__ float s_vec[HD];      // proj, then v
    __shared__ float s_fused[2 * HD];
    __shared__ float s_red[256];
    __shared__ float s_gate[NE];

    for (int i = t; i < SD; i += 256) s_in[i] = smiles[b * SD + i];
    __syncthreads();

    // proj = smiles @ smiles_W + smiles_b   (column t)
    float acc = sb[t];
    #pragma unroll 16
    for (int k = 0; k < SD; ++k) acc = fmaf(s_in[k], sW[k * HD + t], acc);
    s_vec[t] = acc;
    s_fused[HD + t] = acc;
    __syncthreads();

    // v = proj @ Wv + bv
    float v = bv[t];
    #pragma unroll 16
    for (int k = 0; k < HD; ++k) v = fmaf(s_vec[k], Wv[k * HD + t], v);
    __syncthreads();
    s_vec[t] = v;
    __syncthreads();

    // attended = v @ Wo + bo   (attn weight == 1 exactly: softmax over one key)
    float att = bo[t];
    #pragma unroll 16
    for (int k = 0; k < HD; ++k) att = fmaf(s_vec[k], Wo[k * HD + t], att);
    s_fused[t] = att;
    __syncthreads();

    // persist fused = [attended, proj]
    fused_out[b * 2 * HD + t] = s_fused[t];
    fused_out[b * 2 * HD + HD + t] = s_fused[HD + t];

    // gate logits: 32 chunks (of 16 d-values) x 8 experts
    int e = t & 7, chunk = t >> 3;
    float gp = 0.f;
    #pragma unroll
    for (int j = 0; j < 16; ++j) {
        int d = chunk * 16 + j;
        gp = fmaf(s_fused[d], gW[d * NE + e], gp);
    }
    s_red[t] = gp;
    __syncthreads();
    for (int off = 128; off >= 8; off >>= 1) {   // offsets stay multiples of 8 -> preserves e (mod 8)
        if (t < off) s_red[t] += s_red[t + off];
        __syncthreads();
    }
    if (t < NE) s_gate[t] = s_red[t] + gb[t];
    __syncthreads();

    if (t == 0) {
        float m = s_gate[0];
        for (int i = 1; i < NE; ++i) m = fmaxf(m, s_gate[i]);
        float ex[NE], ssum = 0.f;
        for (int i = 0; i < NE; ++i) { ex[i] = expf(s_gate[i] - m); ssum += ex[i]; }
        float pr[NE];
        for (int i = 0; i < NE; ++i) { pr[i] = ex[i] / ssum; probs_out[b * NE + i] = pr[i]; }
        // top-2, first-occurrence tie-break (matches jax.lax.top_k)
        int i1 = 0;
        for (int i = 1; i < NE; ++i) if (pr[i] > pr[i1]) i1 = i;
        int i2 = (i1 == 0) ? 1 : 0;
        for (int i = 0; i < NE; ++i) if (i != i1 && pr[i] > pr[i2]) i2 = i;
        float p1 = pr[i1], p2 = pr[i2], s12 = p1 + p2;
        sel_out[b * 2 + 0] = i1;
        sel_out[b * 2 + 1] = i2;
        p_out[b * 2 + 0] = p1 / s12;
        p_out[b * 2 + 1] = p2 / s12;
    }
}

// Kernel B: dense all-expert first GEMM + exact GELU.
// grid (8 experts, 8 col-tiles of 64), block 512 = 64 cols x 8 b-groups (4 rows each).
// Weights read exactly once across the whole grid (weight-stationary over b).
__global__ __launch_bounds__(512) void expertH1(
    const float* __restrict__ fused, const float* __restrict__ W1,
    const float* __restrict__ b1, float* __restrict__ h1out)
{
    int e = blockIdx.x;
    int ct = blockIdx.y;
    int t = threadIdx.x;
    int c = ct * 64 + (t & 63);
    int bg = t >> 6;   // 0..7, wave-uniform -> LDS broadcasts
    __shared__ float s_f[NB][D2];   // 64 KB

    const float4* fsrc = (const float4*)fused;
    float4* sdst = (float4*)&s_f[0][0];
    for (int i = t; i < NB * D2 / 4; i += 512) sdst[i] = fsrc[i];
    __syncthreads();

    const float* W = W1 + (size_t)e * D2 * D2;
    float bias = b1[e * D2 + c];
    float a0 = bias, a1 = bias, a2 = bias, a3 = bias;
    #pragma unroll 4
    for (int k = 0; k < D2; ++k) {
        float w = W[k * D2 + c];
        a0 = fmaf(w, s_f[bg * 4 + 0][k], a0);
        a1 = fmaf(w, s_f[bg * 4 + 1][k], a1);
        a2 = fmaf(w, s_f[bg * 4 + 2][k], a2);
        a3 = fmaf(w, s_f[bg * 4 + 3][k], a3);
    }
    float* dst = h1out + (size_t)e * NB * D2;
    dst[(bg * 4 + 0) * D2 + c] = gelu_exact(a0);
    dst[(bg * 4 + 1) * D2 + c] = gelu_exact(a1);
    dst[(bg * 4 + 2) * D2 + c] = gelu_exact(a2);
    dst[(bg * 4 + 3) * D2 + c] = gelu_exact(a3);
}

// Kernel C: dense all-expert second GEMM (+ bias).
// grid (8 experts, 4 col-tiles of 64), block 512 = 64 cols x 8 b-groups (4 rows each).
__global__ __launch_bounds__(512) void expertOut(
    const float* __restrict__ h1, const float* __restrict__ W2,
    const float* __restrict__ b2, float* __restrict__ eout)
{
    int e = blockIdx.x;
    int ot = blockIdx.y;
    int t = threadIdx.x;
    int o = ot * 64 + (t & 63);
    int bg = t >> 6;
    __shared__ float s_h[NB][D2];   // 64 KB

    const float4* src = (const float4*)(h1 + (size_t)e * NB * D2);
    float4* dst4 = (float4*)&s_h[0][0];
    for (int i = t; i < NB * D2 / 4; i += 512) dst4[i] = src[i];
    __syncthreads();

    const float* W = W2 + (size_t)e * D2 * HD;
    float bias = b2[e * HD + o];
    float a0 = bias, a1 = bias, a2 = bias, a3 = bias;
    #pragma unroll 4
    for (int k = 0; k < D2; ++k) {
        float w = W[k * HD + o];
        a0 = fmaf(w, s_h[bg * 4 + 0][k], a0);
        a1 = fmaf(w, s_h[bg * 4 + 1][k], a1);
        a2 = fmaf(w, s_h[bg * 4 + 2][k], a2);
        a3 = fmaf(w, s_h[bg * 4 + 3][k], a3);
    }
    float* out = eout + (size_t)e * NB * HD;
    out[(bg * 4 + 0) * HD + o] = a0;
    out[(bg * 4 + 1) * HD + o] = a1;
    out[(bg * 4 + 2) * HD + o] = a2;
    out[(bg * 4 + 3) * HD + o] = a3;
}

// Kernel D: gather top-2, combine, LayerNorm, classifier; block 0 computes aux.
__global__ __launch_bounds__(256) void finalize(
    const float* __restrict__ eout, const float* __restrict__ probs,
    const float* __restrict__ pnorm, const int* __restrict__ sel,
    const float* __restrict__ lng, const float* __restrict__ lnb,
    const float* __restrict__ clsW, const float* __restrict__ clsb,
    float* __restrict__ out)
{
    int b = blockIdx.x, t = threadIdx.x;
    __shared__ float s_red[256];
    __shared__ float s_stats[4];

    int e0 = sel[b * 2 + 0], e1 = sel[b * 2 + 1];
    float p0 = pnorm[b * 2 + 0], p1 = pnorm[b * 2 + 1];
    float moe = p0 * eout[((size_t)e0 * NB + b) * HD + t]
              + p1 * eout[((size_t)e1 * NB + b) * HD + t];

    // mean
    s_red[t] = moe; __syncthreads();
    for (int off = 128; off > 0; off >>= 1) {
        if (t < off) s_red[t] += s_red[t + off];
        __syncthreads();
    }
    if (t == 0) s_stats[0] = s_red[0] * (1.f / HD);
    __syncthreads();
    float mu = s_stats[0];
    float d = moe - mu;

    // variance (population)
    s_red[t] = d * d; __syncthreads();
    for (int off = 128; off > 0; off >>= 1) {
        if (t < off) s_red[t] += s_red[t + off];
        __syncthreads();
    }
    if (t == 0) s_stats[1] = s_red[0] * (1.f / HD);
    __syncthreads();

    float xn = d * rsqrtf(s_stats[1] + 1e-5f);
    float y = fmaf(xn, lng[t], lnb[t]);

    // classifier column 0
    s_red[t] = y * clsW[t * 2 + 0]; __syncthreads();
    for (int off = 128; off > 0; off >>= 1) {
        if (t < off) s_red[t] += s_red[t + off];
        __syncthreads();
    }
    if (t == 0) s_stats[2] = s_red[0] + clsb[0];
    __syncthreads();

    // classifier column 1
    s_red[t] = y * clsW[t * 2 + 1]; __syncthreads();
    for (int off = 128; off > 0; off >>= 1) {
        if (t < off) s_red[t] += s_red[t + off];
        __syncthreads();
    }
    if (t == 0) {
        out[b * 2 + 0] = s_stats[2];
        out[b * 2 + 1] = s_red[0] + clsb[1];
    }

    // aux loss (block 0 only; needs all 32x8 gate probs)
    if (blockIdx.x == 0) {
        __syncthreads();
        s_red[t] = probs[t];   // t encodes (b = t/8, e = t%8)
        __syncthreads();
        for (int off = 128; off >= 8; off >>= 1) {
            if (t < off) s_red[t] += s_red[t + off];
            __syncthreads();
        }
        if (t == 0) {
            float aux = 0.f;
            for (int e = 0; e < NE; ++e) {
                float u = s_red[e] * (1.f / 32.f);
                aux += u * logf(0.125f) - logf(u) * 0.125f;
            }
            out[64] = 0.1f * aux;
        }
    }
}

extern "C" void kernel_launch(void* const* d_in, const int* in_sizes, int n_in,
                              void* d_out, int out_size, void* d_ws, size_t ws_size,
                              hipStream_t stream) {
    (void)in_sizes; (void)n_in; (void)out_size; (void)ws_size;
    // setup_inputs order:
    // 0 eeg_windows (dead), 1 padding_mask (dead), 2 smiles_emb,
    // 3 enc_W (dead), 4 enc_b (dead), 5 agg_W (dead), 6 agg_b (dead),
    // 7 smiles_W, 8 smiles_b, 9 Wq (dead), 10 bq (dead), 11 Wk (dead), 12 bk (dead),
    // 13 Wv, 14 bv, 15 Wo, 16 bo, 17 gate_W, 18 gate_b,
    // 19 exp_W1, 20 exp_b1, 21 exp_W2, 22 exp_b2, 23 ln_g, 24 ln_b, 25 cls_W, 26 cls_b
    const float* smiles = (const float*)d_in[2];
    const float* sW  = (const float*)d_in[7];
    const float* sb  = (const float*)d_in[8];
    const float* Wv  = (const float*)d_in[13];
    const float* bv  = (const float*)d_in[14];
    const float* Wo  = (const float*)d_in[15];
    const float* bo  = (const float*)d_in[16];
    const float* gW  = (const float*)d_in[17];
    const float* gb  = (const float*)d_in[18];
    const float* W1  = (const float*)d_in[19];
    const float* b1  = (const float*)d_in[20];
    const float* W2  = (const float*)d_in[21];
    const float* b2  = (const float*)d_in[22];
    const float* lng = (const float*)d_in[23];
    const float* lnb = (const float*)d_in[24];
    const float* cW  = (const float*)d_in[25];
    const float* cb  = (const float*)d_in[26];
    float* out = (float*)d_out;
    float* ws  = (float*)d_ws;

    float* fused = ws;                       // 32*512      = 16384 floats
    float* probs = ws + 16384;               // 32*8        = 256
    float* pn    = ws + 16640;               // 32*2        = 64
    int*   sel   = (int*)(ws + 16704);       // 32*2        = 64
    float* h1    = ws + 16768;               // 8*32*512    = 131072
    float* eo    = ws + 16768 + 131072;      // 8*32*256    = 65536
    // total ~853 KB of workspace

    stageA<<<32, 256, 0, stream>>>(smiles, sW, sb, Wv, bv, Wo, bo, gW, gb,
                                   fused, probs, pn, sel);
    expertH1<<<dim3(8, 8), 512, 0, stream>>>(fused, W1, b1, h1);
    expertOut<<<dim3(8, 4), 512, 0, stream>>>(h1, W2, b2, eo);
    finalize<<<32, 256, 0, stream>>>(eo, probs, pn, sel, lng, lnb, cW, cb, out);
}